// Round 18
// baseline (152.416 us; speedup 1.0000x reference)
//
#include <hip/hip_runtime.h>
#include <hip/hip_bf16.h>
#include <stdint.h>
#include <math.h>

// B=32, SQ=196, FDIM=2048, L=1000, EDIM=1024, H=16, DH=64
constexpr int BB   = 32;
constexpr int SQ   = 196;
constexpr int FDIM = 2048;
constexpr int LL   = 1000;
constexpr int EDIM = 1024;
constexpr int HH   = 16;
constexpr int BSQ  = BB * SQ;   // 6272 = 49*128 = 98*64

typedef unsigned short u16;
typedef unsigned int   u32;
typedef __attribute__((ext_vector_type(4)))  float f32x4;
typedef __attribute__((ext_vector_type(16))) float f32x16;
typedef __attribute__((ext_vector_type(8)))  short bf16x8;
typedef __attribute__((ext_vector_type(2)))  int   i32x2;

#define DEV __device__ __forceinline__

DEV u16 f2bf(float f) {
  unsigned u = __float_as_uint(f);
  unsigned r = 0x7FFFu + ((u >> 16) & 1u);   // RNE, inputs finite
  return (u16)((u + r) >> 16);
}

DEV u32 pack2bf(float a, float b) {   // -> v_cvt_pk_bf16_f32 (RNE)
  __hip_bfloat162 h = __float22bfloat162_rn(float2{a, b});
  return *reinterpret_cast<const u32*>(&h);
}

#if __has_builtin(__builtin_amdgcn_exp2f)
#define EXP2F(x) __builtin_amdgcn_exp2f(x)
#else
#define EXP2F(x) exp2f(x)
#endif

DEV f32x16 zero16() {
  f32x16 v;
#pragma unroll
  for (int i = 0; i < 16; ++i) v[i] = 0.f;
  return v;
}

// half-swap: a -> {a_lo, b_lo}, b -> {a_hi, b_hi} across the lane<32/lane>=32 split
#if __has_builtin(__builtin_amdgcn_permlane32_swap)
DEV void half_swap(u32& a, u32& b, int /*hi*/) {
  i32x2 r = __builtin_amdgcn_permlane32_swap((int)a, (int)b, false, false);
  a = (u32)r[0]; b = (u32)r[1];
}
#else
DEV void half_swap(u32& a, u32& b, int hi) {
  const u32 sa = __shfl_xor(a, 32), sb = __shfl_xor(b, 32);
  const u32 na = hi ? sb : a;
  const u32 nb = hi ? b : sa;
  a = na; b = nb;
}
#endif

#define GLDS16(g, l) __builtin_amdgcn_global_load_lds(                         \
    (const __attribute__((address_space(1))) void*)(g),                       \
    (__attribute__((address_space(3))) void*)(l), 16, 0, 0)

// XCD-chunked bijective swizzle (T1/m204)
DEV int xcd_chunk(int bid, int cpx) { return (bid & 7) * cpx + (bid >> 3); }

// ---------------- cvt: all 6 input tensors f32 -> bf16 (R5-proven ~22us) ----
constexpr int C_N0 = BSQ * FDIM / 4;           // features  3,211,264
constexpr int C_N1 = C_N0 + EDIM * FDIM / 4;   // Wq
constexpr int C_N2 = C_N1 + EDIM * EDIM / 4;   // Wk
constexpr int C_N3 = C_N2 + EDIM * EDIM / 4;   // Wv
constexpr int C_N4 = C_N3 + EDIM * EDIM / 4;   // Wo
constexpr int C_N5 = C_N4 + LL * EDIM / 4;     // labels

__global__ __launch_bounds__(256)
void cvt_all(const float* __restrict__ f,  const float* __restrict__ wq,
             const float* __restrict__ wk, const float* __restrict__ wv,
             const float* __restrict__ wo, const float* __restrict__ lab,
             u16* df, u16* dwq, u16* dwk, u16* dwv, u16* dwo, u16* dlab) {
  int i = blockIdx.x * blockDim.x + threadIdx.x;
  const int st = gridDim.x * blockDim.x;
  for (; i < C_N5; i += st) {
    const float* s; u16* d; int j;
    if (i < C_N0)      { s = f;   d = df;   j = i; }
    else if (i < C_N1) { s = wq;  d = dwq;  j = i - C_N0; }
    else if (i < C_N2) { s = wk;  d = dwk;  j = i - C_N1; }
    else if (i < C_N3) { s = wv;  d = dwv;  j = i - C_N2; }
    else if (i < C_N4) { s = wo;  d = dwo;  j = i - C_N3; }
    else               { s = lab; d = dlab; j = i - C_N4; }
    float4 v = reinterpret_cast<const float4*>(s)[j];
    ushort4 o;
    o.x = f2bf(v.x); o.y = f2bf(v.y); o.z = f2bf(v.z); o.w = f2bf(v.w);
    reinterpret_cast<ushort4*>(d)[j] = o;
  }
}

// ---------------- 128x128-tile GEMM body, BK=64, T4 ring + T2 slot-XOR ------
// C = (A[M,K] @ B[128-col tile]^T + bias)*scale for one (tm,tn) 128x128 tile.
// OUTMODE: 0 = bf16 row-major (rr<M guard), 1 = f32 row-major (guard),
//          2 = bf16 TRANSPOSED (V^T) with zero-fill for pad rows rr>=M.
//
// R17 proved T2 swizzle (conflicts 1.68e7 -> 0, -11.5us). With conflicts dead,
// the remaining per-step overhead is staging issue + 2 barriers; the 128^2
// tile amortizes it 4x better: 32 MFMA per {16 frag reads + 8 staged loads +
// 2 barriers} vs 64x128's 8 per {6+6+2} (m93 ladder: 128^2 = 1.51x over 64^2).
// Grid 520 blocks = 2.03/CU; LDS 64KB dbuf -> 2 blocks/CU (grid-limited
// anyway). T4 counted-vmcnt ring kept (R16-proven correct): vmcnt(8) = one
// 8-load stage in flight; sched_barrier(0) fences both sides of each
// s_barrier (rule #18: raw s_barrier is no IR fence).
template<int OUTMODE>
DEV void body128(u16* sAb, u16* sBb, int tm, int tn,
                 const u16* __restrict__ A, const u16* __restrict__ B,
                 const float* __restrict__ bias, void* __restrict__ C,
                 int M, int K, float scale) {
  const int lane = threadIdx.x & 63;
  const int wid  = threadIdx.x >> 6;
  const int wr   = wid >> 1, wc = wid & 1;
  const int lr   = lane & 15, lg = lane >> 4;

  f32x4 acc[4][4];
#pragma unroll
  for (int m = 0; m < 4; ++m)
#pragma unroll
    for (int n = 0; n < 4; ++n) acc[m][n] = (f32x4){0.f, 0.f, 0.f, 0.f};

  // 8 loads per stage (A:4 + B:4, 128x64 tiles) -> vmcnt(8) = one stage back.
  // Source col slot-XOR'd by dest row (T2 write-side half).
  auto stage = [&](int buf, int k0) {
#pragma unroll
    for (int i = 0; i < 4; ++i) {
      const int chunk = wid * 4 + i;          // 0..15
      const int row = chunk * 8 + (lane >> 3);
      const int sl  = (lane & 7) ^ (row & 7);
      int ga = tm * 128 + row; ga = ga < M ? ga : M - 1;
      GLDS16(A + (size_t)ga * K + k0 + sl * 8, &sAb[buf * 8192 + chunk * 512]);
    }
#pragma unroll
    for (int i = 0; i < 4; ++i) {
      const int chunk = wid * 4 + i;          // 0..15
      const int row = chunk * 8 + (lane >> 3);
      const int sl  = (lane & 7) ^ (row & 7);
      GLDS16(B + (size_t)(tn * 128 + row) * K + k0 + sl * 8, &sBb[buf * 8192 + chunk * 512]);
    }
  };

  const int NK = K >> 6;                      // 32 (qproj) / 16 (KV, oproj)
  stage(0, 0);
  stage(1, 64);
  asm volatile("s_waitcnt vmcnt(8)" ::: "memory");
  __builtin_amdgcn_sched_barrier(0);
  __builtin_amdgcn_s_barrier();
  __builtin_amdgcn_sched_barrier(0);

  for (int t = 0; t < NK; ++t) {
    const u16* pA = sAb + (t & 1) * 8192;
    const u16* pB = sBb + (t & 1) * 8192;
#pragma unroll
    for (int ks = 0; ks < 2; ++ks) {
      const int sl = ((ks * 4 + lg) ^ (lr & 7)) * 8;   // T2 read-side XOR
      bf16x8 af[4], bfr[4];
#pragma unroll
      for (int m = 0; m < 4; ++m)
        af[m] = *reinterpret_cast<const bf16x8*>(&pA[(wr * 64 + m * 16 + lr) * 64 + sl]);
#pragma unroll
      for (int n = 0; n < 4; ++n)
        bfr[n] = *reinterpret_cast<const bf16x8*>(&pB[(wc * 64 + n * 16 + lr) * 64 + sl]);
#pragma unroll
      for (int m = 0; m < 4; ++m)
#pragma unroll
        for (int n = 0; n < 4; ++n)
          acc[m][n] = __builtin_amdgcn_mfma_f32_16x16x32_bf16(af[m], bfr[n], acc[m][n], 0, 0, 0);
    }
    __builtin_amdgcn_sched_barrier(0);        // pin compute ABOVE barrier #1
    __builtin_amdgcn_s_barrier();             // #1: buf[t&1] reads done block-wide
    __builtin_amdgcn_sched_barrier(0);
    if (t + 2 < NK) {
      stage(t & 1, (t + 2) << 6);             // overwrite just-consumed buffer
      asm volatile("s_waitcnt vmcnt(8)" ::: "memory");   // k(t+1) landed (issued 1 iter ago)
    } else {
      asm volatile("s_waitcnt vmcnt(0)" ::: "memory");   // tail drain
    }
    __builtin_amdgcn_sched_barrier(0);
    __builtin_amdgcn_s_barrier();             // #2: landing made global
    __builtin_amdgcn_sched_barrier(0);
  }

#pragma unroll
  for (int n = 0; n < 4; ++n) {
    const int c = tn * 128 + wc * 64 + n * 16 + lr;
    const float bv = bias[c];
#pragma unroll
    for (int m = 0; m < 4; ++m) {
#pragma unroll
      for (int r = 0; r < 4; ++r) {
        const int rr = tm * 128 + wr * 64 + m * 16 + lg * 4 + r;
        const float v = (acc[m][n][r] + bv) * scale;
        if (OUTMODE == 0)      { if (rr < M) ((u16*)C)[(size_t)rr * 1024 + c] = f2bf(v); }
        else if (OUTMODE == 1) { if (rr < M) ((float*)C)[(size_t)rr * 1024 + c] = v; }
        else                   { ((u16*)C)[(size_t)c * 1024 + rr] = (rr < M) ? f2bf(v) : (u16)0; }
      }
    }
  }
}

// Q-proj (blocks 0..391, 49x8 tiles) + KV GEMM (392..519, 8 tm x 16 tn).
__global__ __launch_bounds__(256)
void gemm_qproj_kv(const u16* fA, const u16* wqb, const float* bq, u16* qo, float qscale,
                   const u16* lab, const u16* wk, const float* bk, u16* ko,
                   const u16* wv, const float* bv, u16* vto) {
  __shared__ __attribute__((aligned(16))) u16 smem[32768];   // 64KB: sA dbuf 32K + sB dbuf 32K
  const int bid = blockIdx.x;
  if (bid < 392) {
    const int nb = xcd_chunk(bid, 49);        // 392 = 8*49, tn fastest within chunk
    body128<0>(smem, smem + 16384, nb / 8, nb % 8, fA, wqb, bq, qo, BSQ, FDIM, qscale);
  } else {
    int nb = xcd_chunk(bid - 392, 16);        // 128 = 8*16
    nb = (nb % 8) * 16 + (nb / 8);            // tm-fastest within chunk
    const int tn16 = nb % 16, tm16 = nb / 16;
    if (tn16 < 8)
      body128<0>(smem, smem + 16384, tm16, tn16, lab, wk, bk, ko, LL, EDIM, 1.0f);
    else
      body128<2>(smem, smem + 16384, tm16, tn16 - 8, lab, wv, bv, vto, LL, EDIM, 1.0f);
  }
}

__global__ __launch_bounds__(256)
void gemm_oproj(const u16* A, const u16* B, const float* bias, float* C) {
  __shared__ __attribute__((aligned(16))) u16 smem[32768];   // 64KB
  const int nb = xcd_chunk(blockIdx.x, 49);   // 392 = 8*49
  body128<1>(smem, smem + 16384, nb / 8, nb % 8, A, B, bias, C, BSQ, EDIM, 1.0f);
}

// ---------------- Flash attention, swapped-operand 32x32 MFMA ----------------
// 1D grid 784 = 8*98, XCD-chunked: XCD owns heads {2x,2x+1} -> per-XCD K/VT
// working set 512KB pinned in L2. Logical id: h = wg/49, qb = wg%49.
// 4 waves/block, wave owns 32 q-rows of the flat (b,sq) axis, LBLK=64.
// S^T = mfma(K, Q): lane holds q=lane&31 column -> softmax in-lane. Q pre-scaled
// by 0.125*log2e at Q-proj -> P = exp2(S^T). P packed bf16 via v_cvt_pk; PV
// B-frags via permlane32_swap. ctx^T = mfma(V^T, P^T). K/VT staged via
// global_load_lds + slot-XOR swizzle, double-buffered, 1 barrier/iter.
// s_setprio(1) around MFMA clusters (T5).
__global__ __launch_bounds__(256, 2)
void attn_kernel(const u16* __restrict__ Q, const u16* __restrict__ Kb,
                 const u16* __restrict__ VT, u16* __restrict__ ctx) {
  const int wg = xcd_chunk(blockIdx.x, 98);   // 784 = 8*98
  const int h = wg / 49, qb = wg % 49;
  __shared__ __attribute__((aligned(16))) u16 sm[16384];  // 32KB: K dbuf 16K + VT dbuf 16K

  const int t    = threadIdx.x;
  const int lane = t & 63;
  const int wid  = t >> 6;
  const int l31  = lane & 31, hi = lane >> 5;

  // Q B-fragments (cols q = lane&31); rows are exact (6272 % 128 == 0)
  const int qrow = qb * 128 + wid * 32 + l31;
  const u16* qp = Q + (size_t)qrow * EDIM + h * 64;
  bf16x8 qf[4];
#pragma unroll
  for (int ks = 0; ks < 4; ++ks)
    qf[ks] = *reinterpret_cast<const bf16x8*>(qp + ks * 16 + hi * 8);

  f32x16 ctxa[2]; ctxa[0] = zero16(); ctxa[1] = zero16();
  float lsum = 0.f;

  // stage one 64-key tile (K rows + VT rows), slot-XOR pre-swizzled source
  auto stage = [&](int buf, int l0s) {
#pragma unroll
    for (int i = 0; i < 2; ++i) {
      const int chunk = wid * 2 + i;                 // 0..7 (1KB chunks)
      const int row   = chunk * 8 + (lane >> 3);     // 0..63
      const int sl    = (lane & 7) ^ (row & 7);
      int lk = l0s + row; if (lk > LL - 1) lk = LL - 1;
      GLDS16(Kb + (size_t)lk * EDIM + h * 64 + sl * 8, sm + buf * 4096 + chunk * 512);
      GLDS16(VT + (size_t)(h * 64 + row) * 1024 + l0s + sl * 8, sm + 8192 + buf * 4096 + chunk * 512);
    }
  };
  // swizzled fragment read: 16B at (row, slot^(row&7))
  auto frag = [&](const u16* base, int row, int slot) -> bf16x8 {
    return *reinterpret_cast<const bf16x8*>(base + row * 64 + ((slot ^ (row & 7)) * 8));
  };

  constexpr int NT = (LL + 63) / 64;  // 16
  stage(0, 0);
  asm volatile("s_waitcnt vmcnt(0)" ::: "memory");
  __syncthreads();

  for (int it = 0; it < NT; ++it) {
    const int l0  = it * 64;
    const int cur = it & 1;
    if (it + 1 < NT) stage(cur ^ 1, l0 + 64);

    const u16* sKb = sm + cur * 4096;
    const u16* sVb = sm + 8192 + cur * 4096;

    // S^T tiles (64k x 32q): A = K rows, B = Q
    f32x16 st[2]; st[0] = zero16(); st[1] = zero16();
    __builtin_amdgcn_s_setprio(1);
#pragma unroll
    for (int ks = 0; ks < 4; ++ks) {
#pragma unroll
      for (int jt = 0; jt < 2; ++jt) {
        bf16x8 kf = frag(sKb, jt * 32 + l31, 2 * ks + hi);
        st[jt] = __builtin_amdgcn_mfma_f32_32x32x16_bf16(kf, qf[ks], st[jt], 0, 0, 0);
      }
    }
    __builtin_amdgcn_s_setprio(0);

    // P = exp2(S^T) + bf16 pack, in-lane (k_row = j + 8g + 4hi within 32-subtile)
    u32 pk[2][4][2];
    auto softmax_pack = [&](bool tail) {
#pragma unroll
      for (int jt = 0; jt < 2; ++jt) {
#pragma unroll
        for (int g = 0; g < 4; ++g) {
          float p[4];
#pragma unroll
          for (int j = 0; j < 4; ++j) {
            float e = EXP2F(st[jt][g * 4 + j]);
            if (tail) {
              const int kg = l0 + jt * 32 + j + 8 * g + 4 * hi;
              if (kg >= LL) e = 0.f;
            }
            p[j] = e;
            lsum += e;
          }
          pk[jt][g][0] = pack2bf(p[0], p[1]);
          pk[jt][g][1] = pack2bf(p[2], p[3]);
        }
      }
    };
    if (l0 + 64 <= LL) softmax_pack(false); else softmax_pack(true);

    // PV: ctx^T += V^T @ P^T.  B-frag slice ksl (jt=ksl>>1, e2=ksl&1): lane(q,hi)
    // needs g=2*e2+hi rows: d0,d1 from lane q (lo), d2,d3 from lane q+32 (hi) --
    // exactly half_swap of the g=2e2 / g=2e2+1 dword pairs.
    __builtin_amdgcn_s_setprio(1);
#pragma unroll
    for (int ksl = 0; ksl < 4; ++ksl) {
      const int jt = ksl >> 1, e2 = ksl & 1;
      u32 x0 = pk[jt][2 * e2 + 0][0], y0 = pk[jt][2 * e2 + 1][0];
      u32 x1 = pk[jt][2 * e2 + 0][1], y1 = pk[jt][2 * e2 + 1][1];
      half_swap(x0, y0, hi);
      half_swap(x1, y1, hi);
      union { u32 d[4]; bf16x8 v; } pf;
      pf.d[0] = x0; pf.d[1] = x1; pf.d[2] = y0; pf.d[3] = y1;
#pragma unroll
      for (int dt = 0; dt < 2; ++dt) {
        bf16x8 vf = frag(sVb, dt * 32 + l31, 2 * ksl + hi);
        ctxa[dt] = __builtin_amdgcn_mfma_f32_32x32x16_bf16(vf, pf.v, ctxa[dt], 0, 0, 0);
      }
    }
    __builtin_amdgcn_s_setprio(0);

    asm volatile("s_waitcnt vmcnt(0)" ::: "memory");
    __syncthreads();
  }

  // normalize (lane-local q) and transpose ctx^T -> ctx via swizzled LDS
  float ltot = lsum + __shfl_xor(lsum, 32);
  const float inv = 1.0f / ltot;

  u16* tb = sm;   // [128 q][64 d] bf16, 128B rows, slot-XOR by (q&7)<<4
  const int q = wid * 32 + l31;
#pragma unroll
  for (int dt = 0; dt < 2; ++dt) {
#pragma unroll
    for (int g = 0; g < 4; ++g) {
      u32 w0 = pack2bf(ctxa[dt][g * 4 + 0] * inv, ctxa[dt][g * 4 + 1] * inv);
      u32 w1 = pack2bf(ctxa[dt][g * 4 + 2] * inv, ctxa[dt][g * 4 + 3] * inv);
      const int d2   = dt * 64 + g * 16 + hi * 8;          // byte offset of d0 within row
      const int byte = q * 128 + (d2 ^ ((q & 7) << 4));
      *reinterpret_cast<u32*>(reinterpret_cast<char*>(tb) + byte)     = w0;
      *reinterpret_cast<u32*>(reinterpret_cast<char*>(tb) + byte + 4) = w1;
    }
  }
  __syncthreads();
#pragma unroll
  for (int pass = 0; pass < 4; ++pass) {
    const int row  = pass * 32 + (t >> 3);
    const int srow = qb * 128 + row;     // always < 6272
    const int cb = ((t & 7) * 16) ^ ((row & 7) << 4);
    uint4 val = *reinterpret_cast<const uint4*>(reinterpret_cast<const char*>(tb) + row * 128 + cb);
    *reinterpret_cast<uint4*>(ctx + (size_t)srow * EDIM + h * 64 + (t & 7) * 8) = val;
  }
}

// ---------------- launch ----------------
extern "C" void kernel_launch(void* const* d_in, const int* in_sizes, int n_in,
                              void* d_out, int out_size, void* d_ws, size_t ws_size,
                              hipStream_t stream) {
  const float* features = (const float*)d_in[0];
  const float* labels   = (const float*)d_in[1];
  const float* Wq = (const float*)d_in[2];
  const float* bq = (const float*)d_in[3];
  const float* Wk = (const float*)d_in[4];
  const float* bk = (const float*)d_in[5];
  const float* Wv = (const float*)d_in[6];
  const float* bv = (const float*)d_in[7];
  const float* Wo = (const float*)d_in[8];
  const float* bo = (const float*)d_in[9];
  float* out = (float*)d_out;

  // workspace layout (bf16 elements), ~68 MB
  u16* f_bf   = (u16*)d_ws;
  u16* wq_bf  = f_bf   + (size_t)BSQ  * FDIM;
  u16* wk_bf  = wq_bf  + (size_t)EDIM * FDIM;
  u16* wv_bf  = wk_bf  + (size_t)EDIM * EDIM;
  u16* wo_bf  = wv_bf  + (size_t)EDIM * EDIM;
  u16* lab_bf = wo_bf  + (size_t)EDIM * EDIM;
  u16* q_bf   = lab_bf + (size_t)LL   * EDIM;
  u16* k_bf   = q_bf   + (size_t)BSQ  * EDIM;
  u16* vt_bf  = k_bf   + (size_t)LL   * EDIM;   // [1024][1024], pad zeroed by KV epilogue
  u16* ctx_bf = vt_bf  + (size_t)1024 * 1024;

  // convert all 6 inputs to bf16 (R5-proven config)
  cvt_all<<<2048, 256, 0, stream>>>(features, Wq, Wk, Wv, Wo, labels,
                                    f_bf, wq_bf, wk_bf, wv_bf, wo_bf, lab_bf);

  // Q-proj (392 blocks, 128^2 tiles) + KV GEMM (128 blocks)
  const float qscale = 0.125f * 1.4426950408889634f;
  gemm_qproj_kv<<<392 + 128, 256, 0, stream>>>(
      f_bf, wq_bf, bq, q_bf, qscale,
      lab_bf, wk_bf, bk, k_bf, wv_bf, bv, vt_bf);

  // attention -> ctx bf16 [6272,1024]; 1D grid, XCD-chunked by head pairs
  attn_kernel<<<784, 256, 0, stream>>>(q_bf, k_bf, vt_bf, ctx_bf);

  // out = ctx @ Wo^T + bo   [6272,1024] f32; 128^2 tiles, 392 blocks
  gemm_oproj<<<392, 256, 0, stream>>>(ctx_bf, wo_bf, bo, out);
}

// Round 19
// 143.502 us; speedup vs baseline: 1.0621x; 1.0621x over previous
//
#include <hip/hip_runtime.h>
#include <hip/hip_bf16.h>
#include <stdint.h>
#include <math.h>

// B=32, SQ=196, FDIM=2048, L=1000, EDIM=1024, H=16, DH=64
constexpr int BB   = 32;
constexpr int SQ   = 196;
constexpr int FDIM = 2048;
constexpr int LL   = 1000;
constexpr int EDIM = 1024;
constexpr int HH   = 16;
constexpr int BSQ  = BB * SQ;   // 6272 = 49*128 = 98*64

typedef unsigned short u16;
typedef unsigned int   u32;
typedef __attribute__((ext_vector_type(4)))  float f32x4;
typedef __attribute__((ext_vector_type(16))) float f32x16;
typedef __attribute__((ext_vector_type(8)))  short bf16x8;
typedef __attribute__((ext_vector_type(2)))  int   i32x2;

#define DEV __device__ __forceinline__

DEV u16 f2bf(float f) {
  unsigned u = __float_as_uint(f);
  unsigned r = 0x7FFFu + ((u >> 16) & 1u);   // RNE, inputs finite
  return (u16)((u + r) >> 16);
}

DEV u32 pack2bf(float a, float b) {   // -> v_cvt_pk_bf16_f32 (RNE)
  __hip_bfloat162 h = __float22bfloat162_rn(float2{a, b});
  return *reinterpret_cast<const u32*>(&h);
}

#if __has_builtin(__builtin_amdgcn_exp2f)
#define EXP2F(x) __builtin_amdgcn_exp2f(x)
#else
#define EXP2F(x) exp2f(x)
#endif

DEV f32x16 zero16() {
  f32x16 v;
#pragma unroll
  for (int i = 0; i < 16; ++i) v[i] = 0.f;
  return v;
}

// half-swap: a -> {a_lo, b_lo}, b -> {a_hi, b_hi} across the lane<32/lane>=32 split
#if __has_builtin(__builtin_amdgcn_permlane32_swap)
DEV void half_swap(u32& a, u32& b, int /*hi*/) {
  i32x2 r = __builtin_amdgcn_permlane32_swap((int)a, (int)b, false, false);
  a = (u32)r[0]; b = (u32)r[1];
}
#else
DEV void half_swap(u32& a, u32& b, int hi) {
  const u32 sa = __shfl_xor(a, 32), sb = __shfl_xor(b, 32);
  const u32 na = hi ? sb : a;
  const u32 nb = hi ? b : sa;
  a = na; b = nb;
}
#endif

#define GLDS16(g, l) __builtin_amdgcn_global_load_lds(                         \
    (const __attribute__((address_space(1))) void*)(g),                       \
    (__attribute__((address_space(3))) void*)(l), 16, 0, 0)

// XCD-chunked bijective swizzle (T1/m204)
DEV int xcd_chunk(int bid, int cpx) { return (bid & 7) * cpx + (bid >> 3); }

// ---------------- cvt: all 6 input tensors f32 -> bf16 (R5-proven ~22us) ----
constexpr int C_N0 = BSQ * FDIM / 4;           // features  3,211,264
constexpr int C_N1 = C_N0 + EDIM * FDIM / 4;   // Wq
constexpr int C_N2 = C_N1 + EDIM * EDIM / 4;   // Wk
constexpr int C_N3 = C_N2 + EDIM * EDIM / 4;   // Wv
constexpr int C_N4 = C_N3 + EDIM * EDIM / 4;   // Wo
constexpr int C_N5 = C_N4 + LL * EDIM / 4;     // labels

__global__ __launch_bounds__(256)
void cvt_all(const float* __restrict__ f,  const float* __restrict__ wq,
             const float* __restrict__ wk, const float* __restrict__ wv,
             const float* __restrict__ wo, const float* __restrict__ lab,
             u16* df, u16* dwq, u16* dwk, u16* dwv, u16* dwo, u16* dlab) {
  int i = blockIdx.x * blockDim.x + threadIdx.x;
  const int st = gridDim.x * blockDim.x;
  for (; i < C_N5; i += st) {
    const float* s; u16* d; int j;
    if (i < C_N0)      { s = f;   d = df;   j = i; }
    else if (i < C_N1) { s = wq;  d = dwq;  j = i - C_N0; }
    else if (i < C_N2) { s = wk;  d = dwk;  j = i - C_N1; }
    else if (i < C_N3) { s = wv;  d = dwv;  j = i - C_N2; }
    else if (i < C_N4) { s = wo;  d = dwo;  j = i - C_N3; }
    else               { s = lab; d = dlab; j = i - C_N4; }
    float4 v = reinterpret_cast<const float4*>(s)[j];
    ushort4 o;
    o.x = f2bf(v.x); o.y = f2bf(v.y); o.z = f2bf(v.z); o.w = f2bf(v.w);
    reinterpret_cast<ushort4*>(d)[j] = o;
  }
}

// ---------------- 64x128-tile GEMM body, BK=64, T4 ring + T2 slot-XOR -------
// C = (A[M,K] @ B[128-col tile]^T + bias)*scale for one (tm,tn) tile.
// OUTMODE: 0 = bf16 row-major (rr<M guard), 1 = f32 row-major (guard),
//          2 = bf16 TRANSPOSED (V^T) with zero-fill for pad rows rr>=M.
//
// R17-proven configuration (best known: total 147.7us, conflicts = 0):
// - T2 slot-XOR (rule #21): inverse-swizzled GLOBAL source col (slot^(row&7)),
//   LDS linear for global_load_lds, XOR on frag read. R17: conflicts
//   1.68e7 -> 0, qproj_kv 67.8 -> 56.3us.
// - T4 counted-vmcnt depth-2 ring (R16-proven correct, perf-neutral):
//   vmcnt(6) = one 6-load stage in flight; sched_barrier(0) fences both
//   sides of each raw s_barrier (rule #18: s_barrier is no IR fence).
// - 64x128 tile, 3 blocks/CU. R18 refuted 128^2 (64KB LDS -> occupancy
//   13%, +8us): concurrency beats per-step amortization in this regime.
template<int OUTMODE>
DEV void body64(u16* sAb, u16* sBb, int tm, int tn,
                const u16* __restrict__ A, const u16* __restrict__ B,
                const float* __restrict__ bias, void* __restrict__ C,
                int M, int K, float scale) {
  const int lane = threadIdx.x & 63;
  const int wid  = threadIdx.x >> 6;
  const int lr = lane & 15, lg = lane >> 4;

  f32x4 acc[4][2];
#pragma unroll
  for (int m = 0; m < 4; ++m)
#pragma unroll
    for (int n = 0; n < 2; ++n) acc[m][n] = (f32x4){0.f, 0.f, 0.f, 0.f};

  // 6 loads per stage (A:2 + B:4) -> vmcnt(6) = exactly one stage in flight.
  auto stage = [&](int buf, int k0) {
#pragma unroll
    for (int i = 0; i < 2; ++i) {
      const int chunk = wid * 2 + i;          // 0..7
      const int row = chunk * 8 + (lane >> 3);
      const int sl  = (lane & 7) ^ (row & 7);
      int ga = tm * 64 + row; ga = ga < M ? ga : M - 1;
      GLDS16(A + (size_t)ga * K + k0 + sl * 8, &sAb[buf * 4096 + chunk * 512]);
    }
#pragma unroll
    for (int i = 0; i < 4; ++i) {
      const int chunk = wid * 4 + i;          // 0..15
      const int row = chunk * 8 + (lane >> 3);
      const int sl  = (lane & 7) ^ (row & 7);
      GLDS16(B + (size_t)(tn * 128 + row) * K + k0 + sl * 8, &sBb[buf * 8192 + chunk * 512]);
    }
  };

  const int NK = K >> 6;                      // 32 (qproj) / 16 (oproj, KV)
  stage(0, 0);
  stage(1, 64);
  asm volatile("s_waitcnt vmcnt(6)" ::: "memory");
  __builtin_amdgcn_sched_barrier(0);
  __builtin_amdgcn_s_barrier();
  __builtin_amdgcn_sched_barrier(0);

  for (int t = 0; t < NK; ++t) {
    const u16* pA = sAb + (t & 1) * 4096;
    const u16* pB = sBb + (t & 1) * 8192;
#pragma unroll
    for (int ks = 0; ks < 2; ++ks) {
      bf16x8 af[4], bfr[2];
#pragma unroll
      for (int m = 0; m < 4; ++m) {
        const int sl = ((ks * 4 + lg) ^ (lr & 7)) * 8;   // T2 read-side XOR
        af[m] = *reinterpret_cast<const bf16x8*>(&pA[(m * 16 + lr) * 64 + sl]);
      }
#pragma unroll
      for (int n = 0; n < 2; ++n) {
        const int sl = ((ks * 4 + lg) ^ (lr & 7)) * 8;
        bfr[n] = *reinterpret_cast<const bf16x8*>(&pB[(wid * 32 + n * 16 + lr) * 64 + sl]);
      }
#pragma unroll
      for (int m = 0; m < 4; ++m)
#pragma unroll
        for (int n = 0; n < 2; ++n)
          acc[m][n] = __builtin_amdgcn_mfma_f32_16x16x32_bf16(af[m], bfr[n], acc[m][n], 0, 0, 0);
    }
    __builtin_amdgcn_sched_barrier(0);        // pin compute ABOVE barrier #1
    __builtin_amdgcn_s_barrier();             // #1: buf[t&1] reads done block-wide
    __builtin_amdgcn_sched_barrier(0);
    if (t + 2 < NK) {
      stage(t & 1, (t + 2) << 6);             // overwrite just-consumed buffer
      asm volatile("s_waitcnt vmcnt(6)" ::: "memory");   // k(t+1) landed (issued 1 iter ago)
    } else {
      asm volatile("s_waitcnt vmcnt(0)" ::: "memory");   // tail drain
    }
    __builtin_amdgcn_sched_barrier(0);
    __builtin_amdgcn_s_barrier();             // #2: landing made global
    __builtin_amdgcn_sched_barrier(0);
  }

#pragma unroll
  for (int n = 0; n < 2; ++n) {
    const int c = tn * 128 + wid * 32 + n * 16 + lr;
    const float bv = bias[c];
#pragma unroll
    for (int m = 0; m < 4; ++m) {
#pragma unroll
      for (int r = 0; r < 4; ++r) {
        const int rr = tm * 64 + m * 16 + lg * 4 + r;
        const float v = (acc[m][n][r] + bv) * scale;
        if (OUTMODE == 0)      { if (rr < M) ((u16*)C)[(size_t)rr * 1024 + c] = f2bf(v); }
        else if (OUTMODE == 1) { if (rr < M) ((float*)C)[(size_t)rr * 1024 + c] = v; }
        else                   { ((u16*)C)[(size_t)c * 1024 + rr] = (rr < M) ? f2bf(v) : (u16)0; }
      }
    }
  }
}

// KV GEMM (blocks 0..255, FIRST so the short NK=16 blocks backfill under the
// qproj wave instead of extending the dispatch tail) + Q-proj (256..1039).
// KV: 256 blocks = 16 tm x 16 tn (tn<8 -> K row-major, tn>=8 -> V^T).
__global__ __launch_bounds__(256)
void gemm_qproj_kv(const u16* fA, const u16* wqb, const float* bq, u16* qo, float qscale,
                   const u16* lab, const u16* wk, const float* bk, u16* ko,
                   const u16* wv, const float* bv, u16* vto) {
  __shared__ __attribute__((aligned(16))) u16 smem[24576];   // 48KB: sA dbuf 16K + sB dbuf 32K
  const int bid = blockIdx.x;
  if (bid < 256) {
    const int nb = xcd_chunk(bid, 32);        // 256 = 8*32
    const int tn16 = nb % 16, tm16 = nb / 16;
    if (tn16 < 8)
      body64<0>(smem, smem + 8192, tm16, tn16, lab, wk, bk, ko, LL, EDIM, 1.0f);
    else
      body64<2>(smem, smem + 8192, tm16, tn16 - 8, lab, wv, bv, vto, LL, EDIM, 1.0f);
  } else {
    const int nb = xcd_chunk(bid - 256, 98);  // 784 = 8*98
    body64<0>(smem, smem + 8192, nb / 8, nb % 8, fA, wqb, bq, qo, BSQ, FDIM, qscale);
  }
}

__global__ __launch_bounds__(256)
void gemm_oproj(const u16* A, const u16* B, const float* bias, float* C) {
  __shared__ __attribute__((aligned(16))) u16 smem[24576];   // 48KB
  const int nb = xcd_chunk(blockIdx.x, 98);   // 784 = 8*98
  body64<1>(smem, smem + 8192, nb / 8, nb % 8, A, B, bias, C, BSQ, EDIM, 1.0f);
}

// ---------------- Flash attention, swapped-operand 32x32 MFMA ----------------
// 1D grid 784 = 8*98, XCD-chunked: XCD owns heads {2x,2x+1} -> per-XCD K/VT
// working set 512KB pinned in L2. Logical id: h = wg/49, qb = wg%49.
// 4 waves/block, wave owns 32 q-rows of the flat (b,sq) axis, LBLK=64.
// S^T = mfma(K, Q): lane holds q=lane&31 column -> softmax in-lane. Q pre-scaled
// by 0.125*log2e at Q-proj -> P = exp2(S^T). P packed bf16 via v_cvt_pk; PV
// B-frags via permlane32_swap. ctx^T = mfma(V^T, P^T). K/VT staged via
// global_load_lds + slot-XOR swizzle, double-buffered, 1 barrier/iter.
// s_setprio(1) around MFMA clusters (T5).
__global__ __launch_bounds__(256, 2)
void attn_kernel(const u16* __restrict__ Q, const u16* __restrict__ Kb,
                 const u16* __restrict__ VT, u16* __restrict__ ctx) {
  const int wg = xcd_chunk(blockIdx.x, 98);   // 784 = 8*98
  const int h = wg / 49, qb = wg % 49;
  __shared__ __attribute__((aligned(16))) u16 sm[16384];  // 32KB: K dbuf 16K + VT dbuf 16K

  const int t    = threadIdx.x;
  const int lane = t & 63;
  const int wid  = t >> 6;
  const int l31  = lane & 31, hi = lane >> 5;

  // Q B-fragments (cols q = lane&31); rows are exact (6272 % 128 == 0)
  const int qrow = qb * 128 + wid * 32 + l31;
  const u16* qp = Q + (size_t)qrow * EDIM + h * 64;
  bf16x8 qf[4];
#pragma unroll
  for (int ks = 0; ks < 4; ++ks)
    qf[ks] = *reinterpret_cast<const bf16x8*>(qp + ks * 16 + hi * 8);

  f32x16 ctxa[2]; ctxa[0] = zero16(); ctxa[1] = zero16();
  float lsum = 0.f;

  // stage one 64-key tile (K rows + VT rows), slot-XOR pre-swizzled source
  auto stage = [&](int buf, int l0s) {
#pragma unroll
    for (int i = 0; i < 2; ++i) {
      const int chunk = wid * 2 + i;                 // 0..7 (1KB chunks)
      const int row   = chunk * 8 + (lane >> 3);     // 0..63
      const int sl    = (lane & 7) ^ (row & 7);
      int lk = l0s + row; if (lk > LL - 1) lk = LL - 1;
      GLDS16(Kb + (size_t)lk * EDIM + h * 64 + sl * 8, sm + buf * 4096 + chunk * 512);
      GLDS16(VT + (size_t)(h * 64 + row) * 1024 + l0s + sl * 8, sm + 8192 + buf * 4096 + chunk * 512);
    }
  };
  // swizzled fragment read: 16B at (row, slot^(row&7))
  auto frag = [&](const u16* base, int row, int slot) -> bf16x8 {
    return *reinterpret_cast<const bf16x8*>(base + row * 64 + ((slot ^ (row & 7)) * 8));
  };

  constexpr int NT = (LL + 63) / 64;  // 16
  stage(0, 0);
  asm volatile("s_waitcnt vmcnt(0)" ::: "memory");
  __syncthreads();

  for (int it = 0; it < NT; ++it) {
    const int l0  = it * 64;
    const int cur = it & 1;
    if (it + 1 < NT) stage(cur ^ 1, l0 + 64);

    const u16* sKb = sm + cur * 4096;
    const u16* sVb = sm + 8192 + cur * 4096;

    // S^T tiles (64k x 32q): A = K rows, B = Q
    f32x16 st[2]; st[0] = zero16(); st[1] = zero16();
    __builtin_amdgcn_s_setprio(1);
#pragma unroll
    for (int ks = 0; ks < 4; ++ks) {
#pragma unroll
      for (int jt = 0; jt < 2; ++jt) {
        bf16x8 kf = frag(sKb, jt * 32 + l31, 2 * ks + hi);
        st[jt] = __builtin_amdgcn_mfma_f32_32x32x16_bf16(kf, qf[ks], st[jt], 0, 0, 0);
      }
    }
    __builtin_amdgcn_s_setprio(0);

    // P = exp2(S^T) + bf16 pack, in-lane (k_row = j + 8g + 4hi within 32-subtile)
    u32 pk[2][4][2];
    auto softmax_pack = [&](bool tail) {
#pragma unroll
      for (int jt = 0; jt < 2; ++jt) {
#pragma unroll
        for (int g = 0; g < 4; ++g) {
          float p[4];
#pragma unroll
          for (int j = 0; j < 4; ++j) {
            float e = EXP2F(st[jt][g * 4 + j]);
            if (tail) {
              const int kg = l0 + jt * 32 + j + 8 * g + 4 * hi;
              if (kg >= LL) e = 0.f;
            }
            p[j] = e;
            lsum += e;
          }
          pk[jt][g][0] = pack2bf(p[0], p[1]);
          pk[jt][g][1] = pack2bf(p[2], p[3]);
        }
      }
    };
    if (l0 + 64 <= LL) softmax_pack(false); else softmax_pack(true);

    // PV: ctx^T += V^T @ P^T.  B-frag slice ksl (jt=ksl>>1, e2=ksl&1): lane(q,hi)
    // needs g=2*e2+hi rows: d0,d1 from lane q (lo), d2,d3 from lane q+32 (hi) --
    // exactly half_swap of the g=2e2 / g=2e2+1 dword pairs.
    __builtin_amdgcn_s_setprio(1);
#pragma unroll
    for (int ksl = 0; ksl < 4; ++ksl) {
      const int jt = ksl >> 1, e2 = ksl & 1;
      u32 x0 = pk[jt][2 * e2 + 0][0], y0 = pk[jt][2 * e2 + 1][0];
      u32 x1 = pk[jt][2 * e2 + 0][1], y1 = pk[jt][2 * e2 + 1][1];
      half_swap(x0, y0, hi);
      half_swap(x1, y1, hi);
      union { u32 d[4]; bf16x8 v; } pf;
      pf.d[0] = x0; pf.d[1] = x1; pf.d[2] = y0; pf.d[3] = y1;
#pragma unroll
      for (int dt = 0; dt < 2; ++dt) {
        bf16x8 vf = frag(sVb, dt * 32 + l31, 2 * ksl + hi);
        ctxa[dt] = __builtin_amdgcn_mfma_f32_32x32x16_bf16(vf, pf.v, ctxa[dt], 0, 0, 0);
      }
    }
    __builtin_amdgcn_s_setprio(0);

    asm volatile("s_waitcnt vmcnt(0)" ::: "memory");
    __syncthreads();
  }

  // normalize (lane-local q) and transpose ctx^T -> ctx via swizzled LDS
  float ltot = lsum + __shfl_xor(lsum, 32);
  const float inv = 1.0f / ltot;

  u16* tb = sm;   // [128 q][64 d] bf16, 128B rows, slot-XOR by (q&7)<<4
  const int q = wid * 32 + l31;
#pragma unroll
  for (int dt = 0; dt < 2; ++dt) {
#pragma unroll
    for (int g = 0; g < 4; ++g) {
      u32 w0 = pack2bf(ctxa[dt][g * 4 + 0] * inv, ctxa[dt][g * 4 + 1] * inv);
      u32 w1 = pack2bf(ctxa[dt][g * 4 + 2] * inv, ctxa[dt][g * 4 + 3] * inv);
      const int d2   = dt * 64 + g * 16 + hi * 8;          // byte offset of d0 within row
      const int byte = q * 128 + (d2 ^ ((q & 7) << 4));
      *reinterpret_cast<u32*>(reinterpret_cast<char*>(tb) + byte)     = w0;
      *reinterpret_cast<u32*>(reinterpret_cast<char*>(tb) + byte + 4) = w1;
    }
  }
  __syncthreads();
#pragma unroll
  for (int pass = 0; pass < 4; ++pass) {
    const int row  = pass * 32 + (t >> 3);
    const int srow = qb * 128 + row;     // always < 6272
    const int cb = ((t & 7) * 16) ^ ((row & 7) << 4);
    uint4 val = *reinterpret_cast<const uint4*>(reinterpret_cast<const char*>(tb) + row * 128 + cb);
    *reinterpret_cast<uint4*>(ctx + (size_t)srow * EDIM + h * 64 + (t & 7) * 8) = val;
  }
}

// ---------------- launch ----------------
extern "C" void kernel_launch(void* const* d_in, const int* in_sizes, int n_in,
                              void* d_out, int out_size, void* d_ws, size_t ws_size,
                              hipStream_t stream) {
  const float* features = (const float*)d_in[0];
  const float* labels   = (const float*)d_in[1];
  const float* Wq = (const float*)d_in[2];
  const float* bq = (const float*)d_in[3];
  const float* Wk = (const float*)d_in[4];
  const float* bk = (const float*)d_in[5];
  const float* Wv = (const float*)d_in[6];
  const float* bv = (const float*)d_in[7];
  const float* Wo = (const float*)d_in[8];
  const float* bo = (const float*)d_in[9];
  float* out = (float*)d_out;

  // workspace layout (bf16 elements), ~68 MB
  u16* f_bf   = (u16*)d_ws;
  u16* wq_bf  = f_bf   + (size_t)BSQ  * FDIM;
  u16* wk_bf  = wq_bf  + (size_t)EDIM * FDIM;
  u16* wv_bf  = wk_bf  + (size_t)EDIM * EDIM;
  u16* wo_bf  = wv_bf  + (size_t)EDIM * EDIM;
  u16* lab_bf = wo_bf  + (size_t)EDIM * EDIM;
  u16* q_bf   = lab_bf + (size_t)LL   * EDIM;
  u16* k_bf   = q_bf   + (size_t)BSQ  * EDIM;
  u16* vt_bf  = k_bf   + (size_t)LL   * EDIM;   // [1024][1024], pad zeroed by KV epilogue
  u16* ctx_bf = vt_bf  + (size_t)1024 * 1024;

  // convert all 6 inputs to bf16 (R5-proven config)
  cvt_all<<<2048, 256, 0, stream>>>(features, Wq, Wk, Wv, Wo, labels,
                                    f_bf, wq_bf, wk_bf, wv_bf, wo_bf, lab_bf);

  // KV GEMM (256 blocks, first) + Q-proj (784 blocks)
  const float qscale = 0.125f * 1.4426950408889634f;
  gemm_qproj_kv<<<256 + 784, 256, 0, stream>>>(
      f_bf, wq_bf, bq, q_bf, qscale,
      lab_bf, wk_bf, bk, k_bf, wv_bf, bv, vt_bf);

  // attention -> ctx bf16 [6272,1024]; 1D grid, XCD-chunked by head pairs
  attn_kernel<<<784, 256, 0, stream>>>(q_bf, k_bf, vt_bf, ctx_bf);

  // out = ctx @ Wo^T + bo   [6272,1024] f32
  gemm_oproj<<<784, 256, 0, stream>>>(ctx_bf, wo_bf, bo, out);
}